// Round 6
// baseline (525.363 us; speedup 1.0000x reference)
//
#include <hip/hip_runtime.h>

typedef unsigned short u16;
typedef __attribute__((ext_vector_type(8))) short bfrag;   // 8 x bf16
typedef __attribute__((ext_vector_type(4))) float ffrag;   // 4 x f32

#define LN_EPS 1e-5f

#define GLOAD16(g, l)                                                          \
    __builtin_amdgcn_global_load_lds(                                          \
        (const __attribute__((address_space(1))) void*)(g),                    \
        (__attribute__((address_space(3))) void*)(l), 16, 0, 0)

__device__ __forceinline__ u16 f2bf(float f) {
    unsigned u = __builtin_bit_cast(unsigned, f);
    u += 0x7fffu + ((u >> 16) & 1u);   // RNE
    return (u16)(u >> 16);
}

// windowed token index -> image row index
__device__ __forceinline__ int win_to_img(int tok) {
    int win = tok >> 9, n = tok & 511;
    int wh = win >> 4, ww = (win >> 2) & 3, wd = win & 3;
    int ph = n >> 6, pw = (n >> 3) & 7, pd = n & 7;
    return ((wh * 8 + ph) * 32 + (ww * 8 + pw)) * 32 + (wd * 8 + pd);
}

// LayerNorm over C=512, one wave per token.
__global__ __launch_bounds__(256) void k_ln(const float* __restrict__ x,
                                            const float* __restrict__ w,
                                            const float* __restrict__ b,
                                            u16* __restrict__ out, int windowed) {
    int wave = threadIdx.x >> 6, lane = threadIdx.x & 63;
    int tok = blockIdx.x * 4 + wave;
    int src = windowed ? win_to_img(tok) : tok;
    const float* xr = x + (size_t)src * 512;
    float v[8];
#pragma unroll
    for (int i = 0; i < 2; i++) {
        float4 f = *(const float4*)(xr + i * 256 + lane * 4);
        v[i * 4 + 0] = f.x; v[i * 4 + 1] = f.y; v[i * 4 + 2] = f.z; v[i * 4 + 3] = f.w;
    }
    float s = 0.f;
#pragma unroll
    for (int i = 0; i < 8; i++) s += v[i];
#pragma unroll
    for (int m = 1; m < 64; m <<= 1) s += __shfl_xor(s, m);
    float mean = s * (1.0f / 512.0f);
    float vs = 0.f;
#pragma unroll
    for (int i = 0; i < 8; i++) { float d = v[i] - mean; vs += d * d; }
#pragma unroll
    for (int m = 1; m < 64; m <<= 1) vs += __shfl_xor(vs, m);
    float rstd = rsqrtf(vs * (1.0f / 512.0f) + LN_EPS);
    u16* orow = out + (size_t)tok * 512;
#pragma unroll
    for (int i = 0; i < 2; i++) {
        int c0 = i * 256 + lane * 4;
        ushort4 o;
        o.x = f2bf((v[i * 4 + 0] - mean) * rstd * w[c0 + 0] + b[c0 + 0]);
        o.y = f2bf((v[i * 4 + 1] - mean) * rstd * w[c0 + 1] + b[c0 + 1]);
        o.z = f2bf((v[i * 4 + 2] - mean) * rstd * w[c0 + 2] + b[c0 + 2]);
        o.w = f2bf((v[i * 4 + 3] - mean) * rstd * w[c0 + 3] + b[c0 + 3]);
        *(ushort4*)(orow + c0) = o;
    }
}

// in: f32 [K][Nn] row-major  ->  out: bf16 [Nn][K] (K contiguous)
__global__ __launch_bounds__(256) void k_transpose(const float* __restrict__ in,
                                                   u16* __restrict__ out, int K, int Nn) {
    int idx = blockIdx.x * 256 + threadIdx.x;
    if (idx >= K * Nn) return;
    int n = idx / K, k = idx - n * K;
    out[idx] = f2bf(in[(size_t)k * Nn + n]);
}

// q_ms f32 [8][512][64] -> bf16, pre-scaled by HD^-0.5 = 0.125
__global__ __launch_bounds__(256) void k_qconv(const float* __restrict__ q, u16* __restrict__ out) {
    int idx = blockIdx.x * 256 + threadIdx.x;
    out[idx] = f2bf(q[idx] * 0.125f);
}

// ==== 256x256 GEMM, 8 waves (2Mx4N), per-kstep phase pipeline (T3+T4+T5) ====
// LDS ring: 4 slots x 32KB; slot = one 32-k chunk of A[256][32] + B[256][32],
// XOR-swizzled (phys_chunk = logical ^ ((row^(row>>2))&3)) via pre-swizzled
// global source (linear gload_lds dest) + matching ds_read offset.
// Phase s: stage chunk s+3 (slot (s-1)&3, dead since prev barrier) ->
// ds_read a[8],b[4] of chunk s -> setprio(1) 32 MFMA setprio(0) ->
// vmcnt(8) [chunk s+1 landed; 2 chunks stay in flight] -> s_barrier.
// EPI 0: +bias -> K plain [win][h][key][d] (LDS-staged rows, bn<2)
//              and V^T plain [win][h][d][key] (packed 8B stores, bn>=2)
// EPI 1: +bias, scatter windowed->image, + resid(x) -> f32   (proj -> x1)
// EPI 2: +bias, exact GELU -> bf16 (LDS-staged coalesced rows) (fc1 -> hid)
// EPI 3: +bias, + resid(x1) -> f32                           (fc2 -> out)
template <int EPI>
__global__ __launch_bounds__(512, 2) void k_gemm256(const u16* __restrict__ A,
                                                    const u16* __restrict__ Bt,
                                                    const float* __restrict__ bias,
                                                    void* __restrict__ Cout, int K, int Nn,
                                                    const float* __restrict__ resid,
                                                    void* __restrict__ Cout2) {
    __shared__ u16 sm[65536];   // 4 slots x 16384 u16 (A @0, B @8192 per slot)
    int tid = threadIdx.x;
    int wave = tid >> 6, lane = tid & 63;
    int wm = wave >> 2, wn = wave & 3;

    int gx = Nn >> 8;
    int nwg = gridDim.x;
    int wg = blockIdx.x;
    int wgs = (wg & 7) * (nwg >> 3) + (wg >> 3);   // XCD chunking (nwg%8==0)
    int bn = wgs % gx, bm = wgs / gx;

    // staging: thread tid -> row rowt=(tid>>2) (+128 on pass 1), chunk col tid&3.
    // pre-swizzle source chunk: (tid&3) ^ ((rowt^(rowt>>2))&3)  (row+128 invariant)
    int rowt = tid >> 2;
    int sxo = (((tid & 3) ^ ((rowt ^ (rowt >> 2)) & 3))) * 8;
    const u16* Ag = A + (size_t)(bm * 256 + rowt) * K + sxo;
    const u16* Bg = Bt + (size_t)(bn * 256 + rowt) * K + sxo;

    // fragment reads: row = base + m*16 + fr; phys chunk = g ^ ((fr^(fr>>2))&3)
    int fr = lane & 15, g = lane >> 4;
    int pco = (g ^ ((fr ^ (fr >> 2)) & 3)) * 8;
    int arow0 = wm * 128 + fr;
    int brow0 = wn * 64 + fr;

    ffrag acc[8][4] = {};

#define STAGE(c)                                                               \
    {                                                                          \
        u16* dst = sm + ((c) & 3) * 16384;                                     \
        size_t ko = (size_t)(c) * 32;                                          \
        GLOAD16(Ag + ko, dst + tid * 8);                                       \
        GLOAD16(Ag + ko + (size_t)128 * K, dst + 4096 + tid * 8);              \
        GLOAD16(Bg + ko, dst + 8192 + tid * 8);                                \
        GLOAD16(Bg + ko + (size_t)128 * K, dst + 12288 + tid * 8);             \
    }

    int nt = K >> 5;   // 32-k chunks (16 for K=512, 64 for K=2048)
    STAGE(0); STAGE(1); STAGE(2);
    asm volatile("s_waitcnt vmcnt(8)" ::: "memory");   // chunk 0 landed
    asm volatile("s_barrier" ::: "memory");

#pragma unroll 4
    for (int s = 0; s < nt; ++s) {
        if (s + 3 < nt) STAGE(s + 3);
        const u16* Asl = sm + (s & 3) * 16384;
        const u16* Bsl = Asl + 8192;
        bfrag a[8], b[4];
#pragma unroll
        for (int m = 0; m < 8; m++) a[m] = *(const bfrag*)(Asl + (arow0 + m * 16) * 32 + pco);
#pragma unroll
        for (int n = 0; n < 4; n++) b[n] = *(const bfrag*)(Bsl + (brow0 + n * 16) * 32 + pco);
        __builtin_amdgcn_s_setprio(1);
#pragma unroll
        for (int m = 0; m < 8; m++)
#pragma unroll
            for (int n = 0; n < 4; n++)
                acc[m][n] = __builtin_amdgcn_mfma_f32_16x16x32_bf16(a[m], b[n], acc[m][n], 0, 0, 0);
        __builtin_amdgcn_s_setprio(0);
        if (s + 3 < nt)
            asm volatile("s_waitcnt vmcnt(8)" ::: "memory");   // chunk s+1 landed
        else if (s + 2 < nt)
            asm volatile("s_waitcnt vmcnt(4)" ::: "memory");   // tail drain
        else if (s + 1 < nt)
            asm volatile("s_waitcnt vmcnt(0)" ::: "memory");
        asm volatile("s_barrier" ::: "memory");
    }
#undef STAGE

    int gcb = bn * 256 + wn * 64 + fr;          // global col for fr (+ n*16)
    int grb = bm * 256 + wm * 128;              // global row base (+ row 0..127)

    if constexpr (EPI == 2 || EPI == 0) {
        bool stagedK = (EPI == 2) || (bn < 2);  // EPI0: bn<2 -> K half, else V half
        if (stagedK) {
            // wave-private LDS [128][64] u16, col ^= (row&7)<<3
            u16* ep = sm + wave * 8192;
#pragma unroll
            for (int m = 0; m < 8; m++)
#pragma unroll
                for (int n = 0; n < 4; n++)
#pragma unroll
                    for (int r = 0; r < 4; r++) {
                        int row = m * 16 + g * 4 + r;
                        int col = n * 16 + fr;
                        float val = acc[m][n][r] + bias[gcb + n * 16];
                        if constexpr (EPI == 2)
                            val = 0.5f * val * (1.0f + erff(val * 0.70710678118f));
                        ep[row * 64 + (col ^ ((row & 7) << 3))] = f2bf(val);
                    }
            int hh = (bn * 256 + wn * 64) >> 6;   // EPI0 head index
#pragma unroll
            for (int rd = 0; rd < 16; rd++) {
                int row = rd * 8 + (lane >> 3);
                int ch = (lane & 7) ^ (row & 7);
                int4 v = *(const int4*)(ep + row * 64 + ch * 8);
                if constexpr (EPI == 2) {
                    int grow = grb + row;
                    *(int4*)(&((u16*)Cout)[(size_t)grow * Nn + bn * 256 + wn * 64 + (lane & 7) * 8]) = v;
                } else {
                    int tok = grb + row;
                    int win = tok >> 9, key = tok & 511;
                    *(int4*)(&((u16*)Cout)[(((size_t)(win * 8 + hh)) * 512 + key) * 64 + (lane & 7) * 8]) = v;
                }
            }
        } else {
            // EPI0 V half: V^T [win][h][d][key], 4 consecutive keys packed -> 8B
#pragma unroll
            for (int m = 0; m < 8; m++) {
                int tok0 = grb + m * 16 + g * 4;
                int win = tok0 >> 9, key = tok0 & 511;
#pragma unroll
                for (int n = 0; n < 4; n++) {
                    int col = gcb + n * 16;        // >= 512
                    int hh = (col >> 6) & 7, d = col & 63;
                    float bv = bias[col];
                    ushort4 pk;
                    pk.x = f2bf(acc[m][n][0] + bv);
                    pk.y = f2bf(acc[m][n][1] + bv);
                    pk.z = f2bf(acc[m][n][2] + bv);
                    pk.w = f2bf(acc[m][n][3] + bv);
                    *(ushort4*)(&((u16*)Cout2)[(((size_t)(win * 8 + hh)) * 64 + d) * 512 + key]) = pk;
                }
            }
        }
    } else {
#pragma unroll
        for (int m = 0; m < 8; m++)
#pragma unroll
            for (int n = 0; n < 4; n++) {
                int col = gcb + n * 16;
                float bv = bias[col];
#pragma unroll
                for (int r = 0; r < 4; r++) {
                    int row = grb + m * 16 + g * 4 + r;
                    float val = acc[m][n][r] + bv;
                    if constexpr (EPI == 1) {
                        int ri = win_to_img(row);
                        size_t o = (size_t)ri * 512 + col;
                        ((float*)Cout)[o] = val + resid[o];
                    } else {
                        size_t o = (size_t)row * 512 + col;
                        ((float*)Cout)[o] = val + resid[o];
                    }
                }
            }
    }
}

// Flash attention: 4096 blocks (XCD-chunk swizzled), 4 waves x 16 q-rows.
// kb:  bf16 [win][h][key 512][d 64]  (PLAIN)
// vtb: bf16 [win][h][d 64][key 512]  (PLAIN)
// Staging: global_load_lds w=16 with pre-swizzled SOURCE chunks (linear LDS
// dest); LDS content [row][c] = true[row][c^(row&7)], reads XOR-deswizzle.
__global__ __launch_bounds__(256, 3) void k_attn(const u16* __restrict__ qb,
                                                 const u16* __restrict__ kb,
                                                 const u16* __restrict__ vtb,
                                                 u16* __restrict__ o) {
    __shared__ u16 K0[4096], K1[4096], V0[4096], V1[4096];  // [row 64][64]
    __shared__ u16 Ps[64][72];
    int bid = blockIdx.x;
    int wg = (bid & 7) * 512 + (bid >> 3);   // bijective XCD chunking (4096%8==0)
    int qc = wg & 7;
    int pair = wg >> 3;
    int hh = pair & 7, win = pair >> 3;
    int wave = threadIdx.x >> 6, lane = threadIdx.x & 63;
    const u16* kbw = kb + ((size_t)(win * 8 + hh)) * 512 * 64;
    const u16* vtw = vtb + ((size_t)(win * 8 + hh)) * 64 * 512;

    const u16* qrow = qb + ((size_t)hh * 512 + qc * 64 + (wave << 4) + (lane & 15)) * 64 + (lane >> 4) * 8;
    bfrag aq0 = *(const bfrag*)(qrow);
    bfrag aq1 = *(const bfrag*)(qrow + 32);

    ffrag acc[4] = {};
    float m_run[4], l_run[4];
#pragma unroll
    for (int r = 0; r < 4; r++) { m_run[r] = -1e30f; l_run[r] = 0.0f; }

    int srow = lane >> 3;                        // sub-row within 8-row group
    int sxo = ((lane & 7) ^ srow) * 8;           // pre-swizzled source chunk
    int fr = lane & 15;
    int fkc = lane >> 4;                         // logical k-chunk 0..3
    int kx0 = (fkc ^ (fr & 7)) * 8;              // physical chunk, k 0..31
    int kx1 = ((fkc + 4) ^ (fr & 7)) * 8;        // k 32..63
    int arow = (wave << 4) + fr;

#define STAGE_KV(KS, VS, kc)                                                   \
    {                                                                          \
        GLOAD16(kbw + (size_t)((kc) * 64 + wave * 8 + srow) * 64 + sxo,        \
                KS + wave * 512);                                              \
        GLOAD16(kbw + (size_t)((kc) * 64 + 32 + wave * 8 + srow) * 64 + sxo,   \
                KS + 2048 + wave * 512);                                       \
        GLOAD16(vtw + (size_t)(wave * 8 + srow) * 512 + (kc) * 64 + sxo,       \
                VS + wave * 512);                                              \
        GLOAD16(vtw + (size_t)(32 + wave * 8 + srow) * 512 + (kc) * 64 + sxo,  \
                VS + 2048 + wave * 512);                                       \
    }
#define ATT_COMPUTE(KS, VS)                                                    \
    {                                                                          \
        ffrag s[4] = {};                                                       \
        _Pragma("unroll") for (int j = 0; j < 4; j++) {                        \
            bfrag b0 = *(const bfrag*)(KS + (j * 16 + fr) * 64 + kx0);         \
            s[j] = __builtin_amdgcn_mfma_f32_16x16x32_bf16(aq0, b0, s[j], 0, 0, 0); \
            bfrag b1 = *(const bfrag*)(KS + (j * 16 + fr) * 64 + kx1);         \
            s[j] = __builtin_amdgcn_mfma_f32_16x16x32_bf16(aq1, b1, s[j], 0, 0, 0); \
        }                                                                      \
        _Pragma("unroll") for (int r = 0; r < 4; r++) {                        \
            float mx = fmaxf(fmaxf(s[0][r], s[1][r]), fmaxf(s[2][r], s[3][r]));\
            _Pragma("unroll") for (int d = 1; d < 16; d <<= 1)                 \
                mx = fmaxf(mx, __shfl_xor(mx, d));                             \
            float mnew = fmaxf(m_run[r], mx);                                  \
            float alpha = __expf(m_run[r] - mnew);                             \
            m_run[r] = mnew;                                                   \
            float rs = 0.0f;                                                   \
            _Pragma("unroll") for (int j = 0; j < 4; j++) {                    \
                float p = __expf(s[j][r] - mnew);                              \
                s[j][r] = p;                                                   \
                rs += p;                                                       \
            }                                                                  \
            _Pragma("unroll") for (int d = 1; d < 16; d <<= 1)                 \
                rs += __shfl_xor(rs, d);                                       \
            l_run[r] = l_run[r] * alpha + rs;                                  \
            _Pragma("unroll") for (int j = 0; j < 4; j++) acc[j][r] *= alpha;  \
        }                                                                      \
        _Pragma("unroll") for (int j = 0; j < 4; j++)                          \
            _Pragma("unroll") for (int r = 0; r < 4; r++)                      \
                Ps[(wave << 4) + (lane >> 4) * 4 + r][j * 16 + fr] = f2bf(s[j][r]); \
        bfrag ap0 = *(const bfrag*)(&Ps[arow][fkc * 8]);                       \
        bfrag ap1 = *(const bfrag*)(&Ps[arow][32 + fkc * 8]);                  \
        _Pragma("unroll") for (int j = 0; j < 4; j++) {                        \
            bfrag v0 = *(const bfrag*)(VS + (j * 16 + fr) * 64 + kx0);         \
            acc[j] = __builtin_amdgcn_mfma_f32_16x16x32_bf16(ap0, v0, acc[j], 0, 0, 0); \
            bfrag v1 = *(const bfrag*)(VS + (j * 16 + fr) * 64 + kx1);         \
            acc[j] = __builtin_amdgcn_mfma_f32_16x16x32_bf16(ap1, v1, acc[j], 0, 0, 0); \
        }                                                                      \
    }

    STAGE_KV(K0, V0, 0);
    __syncthreads();
#pragma unroll 1
    for (int kc = 0; kc < 8; kc += 2) {
        if (kc + 1 < 8) STAGE_KV(K1, V1, kc + 1);
        ATT_COMPUTE(K0, V0);
        __syncthreads();
        if (kc + 2 < 8) STAGE_KV(K0, V0, kc + 2);
        ATT_COMPUTE(K1, V1);
        __syncthreads();
    }
#undef STAGE_KV
#undef ATT_COMPUTE

    int row0 = qc * 64 + (wave << 4) + (lane >> 4) * 4;
#pragma unroll
    for (int j = 0; j < 4; j++) {
        int col = hh * 64 + j * 16 + fr;
#pragma unroll
        for (int r = 0; r < 4; r++) {
            float val = acc[j][r] / l_run[r];
            o[((size_t)win * 512 + row0 + r) * 512 + col] = f2bf(val);
        }
    }
}

extern "C" void kernel_launch(void* const* d_in, const int* in_sizes, int n_in,
                              void* d_out, int out_size, void* d_ws, size_t ws_size,
                              hipStream_t stream) {
    const float* x      = (const float*)d_in[0];
    const float* q_ms   = (const float*)d_in[1];
    const float* n1w    = (const float*)d_in[2];
    const float* n1b    = (const float*)d_in[3];
    const float* kv_w   = (const float*)d_in[4];
    const float* kv_b   = (const float*)d_in[5];
    const float* proj_w = (const float*)d_in[6];
    const float* proj_b = (const float*)d_in[7];
    const float* n2w    = (const float*)d_in[8];
    const float* n2b    = (const float*)d_in[9];
    const float* fc1_w  = (const float*)d_in[10];
    const float* fc1_b  = (const float*)d_in[11];
    const float* fc2_w  = (const float*)d_in[12];
    const float* fc2_b  = (const float*)d_in[13];

    char* ws = (char*)d_ws;
    const size_t OFF_XNW = 0;           // bf16 [32768][512]   33,554,432 B
    const size_t OFF_KB  = 33554432;    // bf16 [64][8][512][64]  33,554,432 B
    const size_t OFF_VT  = 67108864;    // bf16 [64][8][64][512]  33,554,432 B
    const size_t OFF_O   = 100663296;   // bf16 [32768][512]   33,554,432 B
    const size_t OFF_HID = 0;           // bf16 [32768][2048] (aliases dead bufs)
    const size_t OFF_X1  = 134217728;   // f32  [32768][512]   67,108,864 B
    const size_t OFF_XN2 = 201326592;   // bf16 [32768][512]   33,554,432 B
    const size_t OFF_W   = 234881024;   // transposed weights + q
    u16* xnw = (u16*)(ws + OFF_XNW);
    u16* kbb = (u16*)(ws + OFF_KB);
    u16* vtb = (u16*)(ws + OFF_VT);
    u16* ob  = (u16*)(ws + OFF_O);
    u16* hid = (u16*)(ws + OFF_HID);
    float* x1 = (float*)(ws + OFF_X1);
    u16* xn2 = (u16*)(ws + OFF_XN2);
    u16* kv_wt   = (u16*)(ws + OFF_W);        // [1024][512]
    u16* proj_wt = kv_wt + 512 * 1024;        // [512][512]
    u16* fc1_wt  = proj_wt + 512 * 512;       // [2048][512]
    u16* fc2_wt  = fc1_wt + 512 * 2048;       // [512][2048]
    u16* qbf     = fc2_wt + 2048 * 512;       // [8][512][64]
    size_t need = OFF_W + (size_t)(512 * 1024 + 512 * 512 + 512 * 2048 + 2048 * 512 + 8 * 512 * 64) * 2;
    if (ws_size < need) return;

    k_ln<<<8192, 256, 0, stream>>>(x, n1w, n1b, xnw, 1);
    k_transpose<<<2048, 256, 0, stream>>>(kv_w, kv_wt, 512, 1024);
    k_transpose<<<1024, 256, 0, stream>>>(proj_w, proj_wt, 512, 512);
    k_transpose<<<4096, 256, 0, stream>>>(fc1_w, fc1_wt, 512, 2048);
    k_transpose<<<4096, 256, 0, stream>>>(fc2_w, fc2_wt, 2048, 512);
    k_qconv<<<1024, 256, 0, stream>>>(q_ms, qbf);

    k_gemm256<0><<<512, 512, 0, stream>>>(xnw, kv_wt, kv_b, kbb, 512, 1024, nullptr, vtb);
    k_attn<<<dim3(4096), 256, 0, stream>>>(qbf, kbb, vtb, ob);
    k_gemm256<1><<<256, 512, 0, stream>>>(ob, proj_wt, proj_b, x1, 512, 512, x, nullptr);
    k_ln<<<8192, 256, 0, stream>>>(x1, n2w, n2b, xn2, 0);
    k_gemm256<2><<<1024, 512, 0, stream>>>(xn2, fc1_wt, fc1_b, hid, 512, 2048, nullptr, nullptr);
    k_gemm256<3><<<256, 512, 0, stream>>>(hid, fc2_wt, fc2_b, d_out, 2048, 512, x1, nullptr);
}

// Round 7
// 485.801 us; speedup vs baseline: 1.0814x; 1.0814x over previous
//
#include <hip/hip_runtime.h>

typedef unsigned short u16;
typedef __attribute__((ext_vector_type(8))) short bfrag;   // 8 x bf16
typedef __attribute__((ext_vector_type(4))) float ffrag;   // 4 x f32

#define LN_EPS 1e-5f

#define GLOAD16(g, l)                                                          \
    __builtin_amdgcn_global_load_lds(                                          \
        (const __attribute__((address_space(1))) void*)(g),                    \
        (__attribute__((address_space(3))) void*)(l), 16, 0, 0)

__device__ __forceinline__ u16 f2bf(float f) {
    unsigned u = __builtin_bit_cast(unsigned, f);
    u += 0x7fffu + ((u >> 16) & 1u);   // RNE
    return (u16)(u >> 16);
}

// windowed token index -> image row index
__device__ __forceinline__ int win_to_img(int tok) {
    int win = tok >> 9, n = tok & 511;
    int wh = win >> 4, ww = (win >> 2) & 3, wd = win & 3;
    int ph = n >> 6, pw = (n >> 3) & 7, pd = n & 7;
    return ((wh * 8 + ph) * 32 + (ww * 8 + pw)) * 32 + (wd * 8 + pd);
}

// LayerNorm over C=512, one wave per token.
__global__ __launch_bounds__(256) void k_ln(const float* __restrict__ x,
                                            const float* __restrict__ w,
                                            const float* __restrict__ b,
                                            u16* __restrict__ out, int windowed) {
    int wave = threadIdx.x >> 6, lane = threadIdx.x & 63;
    int tok = blockIdx.x * 4 + wave;
    int src = windowed ? win_to_img(tok) : tok;
    const float* xr = x + (size_t)src * 512;
    float v[8];
#pragma unroll
    for (int i = 0; i < 2; i++) {
        float4 f = *(const float4*)(xr + i * 256 + lane * 4);
        v[i * 4 + 0] = f.x; v[i * 4 + 1] = f.y; v[i * 4 + 2] = f.z; v[i * 4 + 3] = f.w;
    }
    float s = 0.f;
#pragma unroll
    for (int i = 0; i < 8; i++) s += v[i];
#pragma unroll
    for (int m = 1; m < 64; m <<= 1) s += __shfl_xor(s, m);
    float mean = s * (1.0f / 512.0f);
    float vs = 0.f;
#pragma unroll
    for (int i = 0; i < 8; i++) { float d = v[i] - mean; vs += d * d; }
#pragma unroll
    for (int m = 1; m < 64; m <<= 1) vs += __shfl_xor(vs, m);
    float rstd = rsqrtf(vs * (1.0f / 512.0f) + LN_EPS);
    u16* orow = out + (size_t)tok * 512;
#pragma unroll
    for (int i = 0; i < 2; i++) {
        int c0 = i * 256 + lane * 4;
        ushort4 o;
        o.x = f2bf((v[i * 4 + 0] - mean) * rstd * w[c0 + 0] + b[c0 + 0]);
        o.y = f2bf((v[i * 4 + 1] - mean) * rstd * w[c0 + 1] + b[c0 + 1]);
        o.z = f2bf((v[i * 4 + 2] - mean) * rstd * w[c0 + 2] + b[c0 + 2]);
        o.w = f2bf((v[i * 4 + 3] - mean) * rstd * w[c0 + 3] + b[c0 + 3]);
        *(ushort4*)(orow + c0) = o;
    }
}

// in: f32 [K][Nn] row-major  ->  out: bf16 [Nn][K] (K contiguous)
__global__ __launch_bounds__(256) void k_transpose(const float* __restrict__ in,
                                                   u16* __restrict__ out, int K, int Nn) {
    int idx = blockIdx.x * 256 + threadIdx.x;
    if (idx >= K * Nn) return;
    int n = idx / K, k = idx - n * K;
    out[idx] = f2bf(in[(size_t)k * Nn + n]);
}

// q_ms f32 [8][512][64] -> bf16, pre-scaled by HD^-0.5 = 0.125
__global__ __launch_bounds__(256) void k_qconv(const float* __restrict__ q, u16* __restrict__ out) {
    int idx = blockIdx.x * 256 + threadIdx.x;
    out[idx] = f2bf(q[idx] * 0.125f);
}

// ==== 128x128 GEMM, BK=32, 4 waves (2x2), 2-phase dbuf, 4 blocks/CU ====
// C = A[M,K](bf16,K-contig) @ Bt[Nn,K](bf16,K-contig)^T + bias.
// Chunk-XOR swizzle both-sides: LDS[r][c] = global[r][c ^ f(r)], f(r)=(r^(r>>2))&3,
// via pre-swizzled global SOURCE (linear gload_lds dest); ds_read applies same XOR.
// <=2-way residual bank aliasing (free). grid: bn fastest + XCD chunking.
// Epilogues (bf16 outputs LDS-staged for 128B-coalesced stores):
// EPI 0: +bias -> K [win][h][key][d] (cols<512) / V^T [win][h][d][key] (cols>=512)
// EPI 1: +bias, scatter windowed->image, + resid(x) -> f32   (proj -> x1)
// EPI 2: +bias, exact GELU -> bf16                           (fc1 -> hid)
// EPI 3: +bias, + resid(x1) -> f32                           (fc2 -> out)
template <int EPI>
__global__ __launch_bounds__(256, 4) void k_gemm128(const u16* __restrict__ A,
                                                    const u16* __restrict__ Bt,
                                                    const float* __restrict__ bias,
                                                    void* __restrict__ Cout, int K, int Nn,
                                                    const float* __restrict__ resid,
                                                    void* __restrict__ Cout2) {
    __shared__ u16 As0[4096], Bs0[4096], As1[4096], Bs1[4096];
    int tid = threadIdx.x;
    int wave = tid >> 6, lane = tid & 63;
    int wr = wave >> 1, wc = wave & 1;

    int gx = Nn >> 7;
    int nwg = gridDim.x;
    int wg = blockIdx.x;
    int wgs = (wg & 7) * (nwg >> 3) + (wg >> 3);   // XCD chunking (nwg%8==0)
    int bn = wgs % gx, bm = wgs / gx;

    // staging: thread covers rows rt (and rt+16), chunk lane&3; pre-swizzled src.
    int rt = wave * 32 + (lane >> 2);
    int sxo = ((lane & 3) ^ ((rt ^ (rt >> 2)) & 3)) * 8;
    const u16* Ag = A + (size_t)(bm * 128 + rt) * K + sxo;
    const u16* Bg = Bt + (size_t)(bn * 128 + rt) * K + sxo;

    // fragment reads: row = base16 + fr -> phys chunk = g ^ ((fr^(fr>>2))&3)
    int fr = lane & 15, g = lane >> 4;
    int pco = (g ^ ((fr ^ (fr >> 2)) & 3)) * 8;

    ffrag acc[4][4] = {};

#define STAGE(AS, BS, k0)                                                      \
    {                                                                          \
        GLOAD16(Ag + (k0), AS + wave * 1024);                                  \
        GLOAD16(Ag + (k0) + 16 * K, AS + wave * 1024 + 512);                   \
        GLOAD16(Bg + (k0), BS + wave * 1024);                                  \
        GLOAD16(Bg + (k0) + 16 * K, BS + wave * 1024 + 512);                   \
    }
#define COMPUTE(AS, BS)                                                        \
    {                                                                          \
        bfrag a[4], b[4];                                                      \
        _Pragma("unroll") for (int m = 0; m < 4; m++)                          \
            a[m] = *(const bfrag*)(AS + (wr * 64 + m * 16 + fr) * 32 + pco);   \
        _Pragma("unroll") for (int n = 0; n < 4; n++)                          \
            b[n] = *(const bfrag*)(BS + (wc * 64 + n * 16 + fr) * 32 + pco);   \
        _Pragma("unroll") for (int m = 0; m < 4; m++)                          \
            _Pragma("unroll") for (int n = 0; n < 4; n++)                      \
                acc[m][n] = __builtin_amdgcn_mfma_f32_16x16x32_bf16(           \
                    a[m], b[n], acc[m][n], 0, 0, 0);                           \
    }

    int nt = K >> 5;   // even for all our K
    STAGE(As0, Bs0, 0);
    __syncthreads();
    int t = 0;
    for (; t + 2 < nt; t += 2) {
        STAGE(As1, Bs1, (t + 1) * 32);
        COMPUTE(As0, Bs0);
        __syncthreads();
        STAGE(As0, Bs0, (t + 2) * 32);
        COMPUTE(As1, Bs1);
        __syncthreads();
    }
    STAGE(As1, Bs1, (nt - 1) * 32);
    COMPUTE(As0, Bs0);
    __syncthreads();
    COMPUTE(As1, Bs1);
#undef STAGE
#undef COMPUTE

    int gcolb = bn * 128 + wc * 64;             // wave col base
    int grb = bm * 128 + wr * 64;               // wave row base

    if constexpr (EPI == 0 || EPI == 2) {
        __syncthreads();   // safe to reuse staging LDS
        u16* ep = (wave == 0) ? As0 : (wave == 1) ? Bs0 : (wave == 2) ? As1 : Bs1;
        int h = (gcolb >> 6) & 7;
        bool isK = (EPI == 2) || (gcolb < 512);
#pragma unroll
        for (int m = 0; m < 4; m++)
#pragma unroll
            for (int n = 0; n < 4; n++) {
                float bv = bias[gcolb + n * 16 + fr];
#pragma unroll
                for (int r = 0; r < 4; r++) {
                    int wq = m * 16 + g * 4 + r;     // row within quadrant
                    int wcc = n * 16 + fr;           // col within quadrant
                    float val = acc[m][n][r] + bv;
                    if constexpr (EPI == 2)
                        val = 0.5f * val * (1.0f + erff(val * 0.70710678118f));
                    if (isK)
                        ep[wq * 64 + (wcc ^ ((wq & 7) << 3))] = f2bf(val);
                    else   // V: transpose in LDS -> [d][key]
                        ep[wcc * 64 + (wq ^ ((wcc & 7) << 3))] = f2bf(val);
                }
            }
#pragma unroll
        for (int rd = 0; rd < 8; rd++) {
            int row = rd * 8 + (lane >> 3);
            int ch = (lane & 7) ^ (row & 7);
            int4 v = *(const int4*)(ep + row * 64 + ch * 8);
            if constexpr (EPI == 2) {
                int grow = grb + row;
                *(int4*)(&((u16*)Cout)[(size_t)grow * Nn + gcolb + (lane & 7) * 8]) = v;
            } else {
                if (isK) {
                    int tok = grb + row;
                    int win = tok >> 9, key = tok & 511;
                    *(int4*)(&((u16*)Cout)[(((size_t)(win * 8 + h)) * 512 + key) * 64 + (lane & 7) * 8]) = v;
                } else {
                    int win = grb >> 9, key0 = grb & 511;   // 64 keys same window
                    *(int4*)(&((u16*)Cout2)[(((size_t)(win * 8 + h)) * 64 + row) * 512 + key0 + (lane & 7) * 8]) = v;
                }
            }
        }
    } else {
#pragma unroll
        for (int m = 0; m < 4; m++)
#pragma unroll
            for (int n = 0; n < 4; n++) {
                int col = gcolb + n * 16 + fr;
                float bv = bias[col];
#pragma unroll
                for (int r = 0; r < 4; r++) {
                    int row = grb + m * 16 + g * 4 + r;
                    float val = acc[m][n][r] + bv;
                    if constexpr (EPI == 1) {
                        int ri = win_to_img(row);
                        size_t o = (size_t)ri * 512 + col;
                        ((float*)Cout)[o] = val + resid[o];
                    } else {
                        size_t o = (size_t)row * 512 + col;
                        ((float*)Cout)[o] = val + resid[o];
                    }
                }
            }
    }
}

// Flash attention: 4096 blocks (XCD-chunk swizzled), 4 waves x 16 q-rows.
// kb:  bf16 [win][h][key 512][d 64]  (PLAIN)
// vtb: bf16 [win][h][d 64][key 512]  (PLAIN)
// Staging: global_load_lds w=16 with pre-swizzled SOURCE chunks (linear LDS
// dest); LDS content [row][c] = true[row][c^(row&7)], reads XOR-deswizzle.
__global__ __launch_bounds__(256, 3) void k_attn(const u16* __restrict__ qb,
                                                 const u16* __restrict__ kb,
                                                 const u16* __restrict__ vtb,
                                                 u16* __restrict__ o) {
    __shared__ u16 K0[4096], K1[4096], V0[4096], V1[4096];  // [row 64][64]
    __shared__ u16 Ps[64][72];
    int bid = blockIdx.x;
    int wg = (bid & 7) * 512 + (bid >> 3);   // bijective XCD chunking (4096%8==0)
    int qc = wg & 7;
    int pair = wg >> 3;
    int hh = pair & 7, win = pair >> 3;
    int wave = threadIdx.x >> 6, lane = threadIdx.x & 63;
    const u16* kbw = kb + ((size_t)(win * 8 + hh)) * 512 * 64;
    const u16* vtw = vtb + ((size_t)(win * 8 + hh)) * 64 * 512;

    const u16* qrow = qb + ((size_t)hh * 512 + qc * 64 + (wave << 4) + (lane & 15)) * 64 + (lane >> 4) * 8;
    bfrag aq0 = *(const bfrag*)(qrow);
    bfrag aq1 = *(const bfrag*)(qrow + 32);

    ffrag acc[4] = {};
    float m_run[4], l_run[4];
#pragma unroll
    for (int r = 0; r < 4; r++) { m_run[r] = -1e30f; l_run[r] = 0.0f; }

    int srow = lane >> 3;                        // sub-row within 8-row group
    int sxo = ((lane & 7) ^ srow) * 8;           // pre-swizzled source chunk
    int fr = lane & 15;
    int fkc = lane >> 4;                         // logical k-chunk 0..3
    int kx0 = (fkc ^ (fr & 7)) * 8;              // physical chunk, k 0..31
    int kx1 = ((fkc + 4) ^ (fr & 7)) * 8;        // k 32..63
    int arow = (wave << 4) + fr;

#define STAGE_KV(KS, VS, kc)                                                   \
    {                                                                          \
        GLOAD16(kbw + (size_t)((kc) * 64 + wave * 8 + srow) * 64 + sxo,        \
                KS + wave * 512);                                              \
        GLOAD16(kbw + (size_t)((kc) * 64 + 32 + wave * 8 + srow) * 64 + sxo,   \
                KS + 2048 + wave * 512);                                       \
        GLOAD16(vtw + (size_t)(wave * 8 + srow) * 512 + (kc) * 64 + sxo,       \
                VS + wave * 512);                                              \
        GLOAD16(vtw + (size_t)(32 + wave * 8 + srow) * 512 + (kc) * 64 + sxo,  \
                VS + 2048 + wave * 512);                                       \
    }
#define ATT_COMPUTE(KS, VS)                                                    \
    {                                                                          \
        ffrag s[4] = {};                                                       \
        _Pragma("unroll") for (int j = 0; j < 4; j++) {                        \
            bfrag b0 = *(const bfrag*)(KS + (j * 16 + fr) * 64 + kx0);         \
            s[j] = __builtin_amdgcn_mfma_f32_16x16x32_bf16(aq0, b0, s[j], 0, 0, 0); \
            bfrag b1 = *(const bfrag*)(KS + (j * 16 + fr) * 64 + kx1);         \
            s[j] = __builtin_amdgcn_mfma_f32_16x16x32_bf16(aq1, b1, s[j], 0, 0, 0); \
        }                                                                      \
        _Pragma("unroll") for (int r = 0; r < 4; r++) {                        \
            float mx = fmaxf(fmaxf(s[0][r], s[1][r]), fmaxf(s[2][r], s[3][r]));\
            _Pragma("unroll") for (int d = 1; d < 16; d <<= 1)                 \
                mx = fmaxf(mx, __shfl_xor(mx, d));                             \
            float mnew = fmaxf(m_run[r], mx);                                  \
            float alpha = __expf(m_run[r] - mnew);                             \
            m_run[r] = mnew;                                                   \
            float rs = 0.0f;                                                   \
            _Pragma("unroll") for (int j = 0; j < 4; j++) {                    \
                float p = __expf(s[j][r] - mnew);                              \
                s[j][r] = p;                                                   \
                rs += p;                                                       \
            }                                                                  \
            _Pragma("unroll") for (int d = 1; d < 16; d <<= 1)                 \
                rs += __shfl_xor(rs, d);                                       \
            l_run[r] = l_run[r] * alpha + rs;                                  \
            _Pragma("unroll") for (int j = 0; j < 4; j++) acc[j][r] *= alpha;  \
        }                                                                      \
        _Pragma("unroll") for (int j = 0; j < 4; j++)                          \
            _Pragma("unroll") for (int r = 0; r < 4; r++)                      \
                Ps[(wave << 4) + (lane >> 4) * 4 + r][j * 16 + fr] = f2bf(s[j][r]); \
        bfrag ap0 = *(const bfrag*)(&Ps[arow][fkc * 8]);                       \
        bfrag ap1 = *(const bfrag*)(&Ps[arow][32 + fkc * 8]);                  \
        _Pragma("unroll") for (int j = 0; j < 4; j++) {                        \
            bfrag v0 = *(const bfrag*)(VS + (j * 16 + fr) * 64 + kx0);         \
            acc[j] = __builtin_amdgcn_mfma_f32_16x16x32_bf16(ap0, v0, acc[j], 0, 0, 0); \
            bfrag v1 = *(const bfrag*)(VS + (j * 16 + fr) * 64 + kx1);         \
            acc[j] = __builtin_amdgcn_mfma_f32_16x16x32_bf16(ap1, v1, acc[j], 0, 0, 0); \
        }                                                                      \
    }

    STAGE_KV(K0, V0, 0);
    __syncthreads();
#pragma unroll 1
    for (int kc = 0; kc < 8; kc += 2) {
        if (kc + 1 < 8) STAGE_KV(K1, V1, kc + 1);
        ATT_COMPUTE(K0, V0);
        __syncthreads();
        if (kc + 2 < 8) STAGE_KV(K0, V0, kc + 2);
        ATT_COMPUTE(K1, V1);
        __syncthreads();
    }
#undef STAGE_KV
#undef ATT_COMPUTE

    int row0 = qc * 64 + (wave << 4) + (lane >> 4) * 4;
#pragma unroll
    for (int j = 0; j < 4; j++) {
        int col = hh * 64 + j * 16 + fr;
#pragma unroll
        for (int r = 0; r < 4; r++) {
            float val = acc[j][r] / l_run[r];
            o[((size_t)win * 512 + row0 + r) * 512 + col] = f2bf(val);
        }
    }
}

extern "C" void kernel_launch(void* const* d_in, const int* in_sizes, int n_in,
                              void* d_out, int out_size, void* d_ws, size_t ws_size,
                              hipStream_t stream) {
    const float* x      = (const float*)d_in[0];
    const float* q_ms   = (const float*)d_in[1];
    const float* n1w    = (const float*)d_in[2];
    const float* n1b    = (const float*)d_in[3];
    const float* kv_w   = (const float*)d_in[4];
    const float* kv_b   = (const float*)d_in[5];
    const float* proj_w = (const float*)d_in[6];
    const float* proj_b = (const float*)d_in[7];
    const float* n2w    = (const float*)d_in[8];
    const float* n2b    = (const float*)d_in[9];
    const float* fc1_w  = (const float*)d_in[10];
    const float* fc1_b  = (const float*)d_in[11];
    const float* fc2_w  = (const float*)d_in[12];
    const float* fc2_b  = (const float*)d_in[13];

    char* ws = (char*)d_ws;
    const size_t OFF_XNW = 0;           // bf16 [32768][512]   33,554,432 B
    const size_t OFF_KB  = 33554432;    // bf16 [64][8][512][64]  33,554,432 B
    const size_t OFF_VT  = 67108864;    // bf16 [64][8][64][512]  33,554,432 B
    const size_t OFF_O   = 100663296;   // bf16 [32768][512]   33,554,432 B
    const size_t OFF_HID = 0;           // bf16 [32768][2048] (aliases dead bufs)
    const size_t OFF_X1  = 134217728;   // f32  [32768][512]   67,108,864 B
    const size_t OFF_XN2 = 201326592;   // bf16 [32768][512]   33,554,432 B
    const size_t OFF_W   = 234881024;   // transposed weights + q
    u16* xnw = (u16*)(ws + OFF_XNW);
    u16* kbb = (u16*)(ws + OFF_KB);
    u16* vtb = (u16*)(ws + OFF_VT);
    u16* ob  = (u16*)(ws + OFF_O);
    u16* hid = (u16*)(ws + OFF_HID);
    float* x1 = (float*)(ws + OFF_X1);
    u16* xn2 = (u16*)(ws + OFF_XN2);
    u16* kv_wt   = (u16*)(ws + OFF_W);        // [1024][512]
    u16* proj_wt = kv_wt + 512 * 1024;        // [512][512]
    u16* fc1_wt  = proj_wt + 512 * 512;       // [2048][512]
    u16* fc2_wt  = fc1_wt + 512 * 2048;       // [512][2048]
    u16* qbf     = fc2_wt + 2048 * 512;       // [8][512][64]
    size_t need = OFF_W + (size_t)(512 * 1024 + 512 * 512 + 512 * 2048 + 2048 * 512 + 8 * 512 * 64) * 2;
    if (ws_size < need) return;

    k_ln<<<8192, 256, 0, stream>>>(x, n1w, n1b, xnw, 1);
    k_transpose<<<2048, 256, 0, stream>>>(kv_w, kv_wt, 512, 1024);
    k_transpose<<<1024, 256, 0, stream>>>(proj_w, proj_wt, 512, 512);
    k_transpose<<<4096, 256, 0, stream>>>(fc1_w, fc1_wt, 512, 2048);
    k_transpose<<<4096, 256, 0, stream>>>(fc2_w, fc2_wt, 2048, 512);
    k_qconv<<<1024, 256, 0, stream>>>(q_ms, qbf);

    k_gemm128<0><<<2048, 256, 0, stream>>>(xnw, kv_wt, kv_b, kbb, 512, 1024, nullptr, vtb);
    k_attn<<<dim3(4096), 256, 0, stream>>>(qbf, kbb, vtb, ob);
    k_gemm128<1><<<1024, 256, 0, stream>>>(ob, proj_wt, proj_b, x1, 512, 512, x, nullptr);
    k_ln<<<8192, 256, 0, stream>>>(x1, n2w, n2b, xn2, 0);
    k_gemm128<2><<<4096, 256, 0, stream>>>(xn2, fc1_wt, fc1_b, hid, 512, 2048, nullptr, nullptr);
    k_gemm128<3><<<1024, 256, 0, stream>>>(hid, fc2_wt, fc2_b, d_out, 2048, 512, x1, nullptr);
}

// Round 10
// 480.494 us; speedup vs baseline: 1.0934x; 1.0110x over previous
//
#include <hip/hip_runtime.h>

typedef unsigned short u16;
typedef __attribute__((ext_vector_type(8))) short bfrag;   // 8 x bf16
typedef __attribute__((ext_vector_type(4))) float ffrag;   // 4 x f32

#define LN_EPS 1e-5f

#define GLOAD16(g, l)                                                          \
    __builtin_amdgcn_global_load_lds(                                          \
        (const __attribute__((address_space(1))) void*)(g),                    \
        (__attribute__((address_space(3))) void*)(l), 16, 0, 0)

__device__ __forceinline__ u16 f2bf(float f) {
    unsigned u = __builtin_bit_cast(unsigned, f);
    u += 0x7fffu + ((u >> 16) & 1u);   // RNE
    return (u16)(u >> 16);
}

// windowed token index -> image row index
__device__ __forceinline__ int win_to_img(int tok) {
    int win = tok >> 9, n = tok & 511;
    int wh = win >> 4, ww = (win >> 2) & 3, wd = win & 3;
    int ph = n >> 6, pw = (n >> 3) & 7, pd = n & 7;
    return ((wh * 8 + ph) * 32 + (ww * 8 + pw)) * 32 + (wd * 8 + pd);
}

// LayerNorm over C=512, one wave per token.
__global__ __launch_bounds__(256) void k_ln(const float* __restrict__ x,
                                            const float* __restrict__ w,
                                            const float* __restrict__ b,
                                            u16* __restrict__ out, int windowed) {
    int wave = threadIdx.x >> 6, lane = threadIdx.x & 63;
    int tok = blockIdx.x * 4 + wave;
    int src = windowed ? win_to_img(tok) : tok;
    const float* xr = x + (size_t)src * 512;
    float v[8];
#pragma unroll
    for (int i = 0; i < 2; i++) {
        float4 f = *(const float4*)(xr + i * 256 + lane * 4);
        v[i * 4 + 0] = f.x; v[i * 4 + 1] = f.y; v[i * 4 + 2] = f.z; v[i * 4 + 3] = f.w;
    }
    float s = 0.f;
#pragma unroll
    for (int i = 0; i < 8; i++) s += v[i];
#pragma unroll
    for (int m = 1; m < 64; m <<= 1) s += __shfl_xor(s, m);
    float mean = s * (1.0f / 512.0f);
    float vs = 0.f;
#pragma unroll
    for (int i = 0; i < 8; i++) { float d = v[i] - mean; vs += d * d; }
#pragma unroll
    for (int m = 1; m < 64; m <<= 1) vs += __shfl_xor(vs, m);
    float rstd = rsqrtf(vs * (1.0f / 512.0f) + LN_EPS);
    u16* orow = out + (size_t)tok * 512;
#pragma unroll
    for (int i = 0; i < 2; i++) {
        int c0 = i * 256 + lane * 4;
        ushort4 o;
        o.x = f2bf((v[i * 4 + 0] - mean) * rstd * w[c0 + 0] + b[c0 + 0]);
        o.y = f2bf((v[i * 4 + 1] - mean) * rstd * w[c0 + 1] + b[c0 + 1]);
        o.z = f2bf((v[i * 4 + 2] - mean) * rstd * w[c0 + 2] + b[c0 + 2]);
        o.w = f2bf((v[i * 4 + 3] - mean) * rstd * w[c0 + 3] + b[c0 + 3]);
        *(ushort4*)(orow + c0) = o;
    }
}

// in: f32 [K][Nn] row-major  ->  out: bf16 [Nn][K] (K contiguous)
__global__ __launch_bounds__(256) void k_transpose(const float* __restrict__ in,
                                                   u16* __restrict__ out, int K, int Nn) {
    int idx = blockIdx.x * 256 + threadIdx.x;
    if (idx >= K * Nn) return;
    int n = idx / K, k = idx - n * K;
    out[idx] = f2bf(in[(size_t)k * Nn + n]);
}

// q_ms f32 [8][512][64] -> bf16, pre-scaled by HD^-0.5 = 0.125
__global__ __launch_bounds__(256) void k_qconv(const float* __restrict__ q, u16* __restrict__ out) {
    int idx = blockIdx.x * 256 + threadIdx.x;
    out[idx] = f2bf(q[idx] * 0.125f);
}

// ==== 128x128 GEMM, BK=32, 4 waves (2x2), DEPTH-3 counted-vmcnt pipeline ====
// C = A[M,K](bf16,K-contig) @ Bt[Nn,K](bf16,K-contig)^T + bias.
// 3 LDS slots (48KB -> 3 blocks/CU). Phase t: STAGE tile t+2 into slot
// (t+2)%3 (runtime offsets, offset-imm=0 -- the HW-proven form from R5/R6) ->
// COMPUTE slot t%3 (setprio around MFMA) -> lgkmcnt(0) -> vmcnt(4)
// [tile t+1 landed; t+2 stays in flight] -> sched_barrier|s_barrier|sched_barrier.
// Slot (t+2)%3 was last read in phase t-1, one barrier earlier, lgkm-drained.
// Chunk-XOR swizzle both-sides (pre-swizzled src, deswizzled ds_read).
// Epilogues (bf16 outputs LDS-staged for 128B-coalesced stores):
// EPI 0: +bias -> K [win][h][key][d] (cols<512) / V^T [win][h][d][key] (cols>=512)
// EPI 1: +bias, scatter windowed->image, + resid(x) -> f32   (proj -> x1)
// EPI 2: +bias, exact GELU -> bf16                           (fc1 -> hid)
// EPI 3: +bias, + resid(x1) -> f32                           (fc2 -> out)
template <int EPI>
__global__ __launch_bounds__(256, 3) void k_gemm128(const u16* __restrict__ A,
                                                    const u16* __restrict__ Bt,
                                                    const float* __restrict__ bias,
                                                    void* __restrict__ Cout, int K, int Nn,
                                                    const float* __restrict__ resid,
                                                    void* __restrict__ Cout2) {
    __shared__ u16 sm[24576];   // 3 slots x 8192 u16 (A @0, B @4096 per slot)
    int tid = threadIdx.x;
    int wave = tid >> 6, lane = tid & 63;
    int wr = wave >> 1, wc = wave & 1;

    int gx = Nn >> 7;
    int nwg = gridDim.x;
    int wg = blockIdx.x;
    int wgs = (wg & 7) * (nwg >> 3) + (wg >> 3);   // XCD chunking (nwg%8==0)
    int bn = wgs % gx, bm = wgs / gx;

    // staging: thread covers rows rt (and rt+16), chunk lane&3; pre-swizzled src.
    int rt = wave * 32 + (lane >> 2);
    int sxo = ((lane & 3) ^ ((rt ^ (rt >> 2)) & 3)) * 8;
    const u16* Ag = A + (size_t)(bm * 128 + rt) * K + sxo;
    const u16* Bg = Bt + (size_t)(bn * 128 + rt) * K + sxo;
    int wl = wave * 1024;

    // fragment reads: row = base16 + fr -> phys chunk = g ^ ((fr^(fr>>2))&3)
    int fr = lane & 15, g = lane >> 4;
    int pco = (g ^ ((fr ^ (fr >> 2)) & 3)) * 8;

    ffrag acc[4][4] = {};

#define STAGE(SLOT, k0)                                                        \
    {                                                                          \
        u16* d = sm + (SLOT) * 8192 + wl;                                      \
        GLOAD16(Ag + (k0), d);                                                 \
        GLOAD16(Ag + (k0) + 16 * K, d + 512);                                  \
        GLOAD16(Bg + (k0), d + 4096);                                          \
        GLOAD16(Bg + (k0) + 16 * K, d + 4608);                                 \
    }
#define COMPUTE(SLOT)                                                          \
    {                                                                          \
        const u16* Ab = sm + (SLOT) * 8192;                                    \
        const u16* Bb = Ab + 4096;                                             \
        bfrag a[4], b[4];                                                      \
        _Pragma("unroll") for (int m = 0; m < 4; m++)                          \
            a[m] = *(const bfrag*)(Ab + (wr * 64 + m * 16 + fr) * 32 + pco);   \
        _Pragma("unroll") for (int n = 0; n < 4; n++)                          \
            b[n] = *(const bfrag*)(Bb + (wc * 64 + n * 16 + fr) * 32 + pco);   \
        __builtin_amdgcn_s_setprio(1);                                         \
        _Pragma("unroll") for (int m = 0; m < 4; m++)                          \
            _Pragma("unroll") for (int n = 0; n < 4; n++)                      \
                acc[m][n] = __builtin_amdgcn_mfma_f32_16x16x32_bf16(           \
                    a[m], b[n], acc[m][n], 0, 0, 0);                           \
        __builtin_amdgcn_s_setprio(0);                                         \
    }
// Phase tt (slot SLOT = tt%3): stage tile tt+2, compute tile tt, wait so that
// tile tt+1 is landed before the barrier (tile tt+2 stays in flight).
#define PHASE(tt, SLOT)                                                        \
    if ((tt) < nt) {                                                           \
        if ((tt) + 2 < nt) STAGE(((tt) + 2) % 3, ((tt) + 2) * 32);             \
        COMPUTE(SLOT);                                                         \
        asm volatile("s_waitcnt lgkmcnt(0)" ::: "memory");                     \
        if ((tt) + 2 < nt) {                                                   \
            asm volatile("s_waitcnt vmcnt(4)" ::: "memory");                   \
        } else if ((tt) + 1 < nt) {                                            \
            asm volatile("s_waitcnt vmcnt(0)" ::: "memory");                   \
        }                                                                      \
        __builtin_amdgcn_sched_barrier(0);                                     \
        __builtin_amdgcn_s_barrier();                                          \
        __builtin_amdgcn_sched_barrier(0);                                     \
    }

    int nt = K >> 5;
    STAGE(0, 0);
    STAGE(1, 32);
    asm volatile("s_waitcnt vmcnt(4)" ::: "memory");   // tile 0 landed
    __builtin_amdgcn_sched_barrier(0);
    __builtin_amdgcn_s_barrier();
    __builtin_amdgcn_sched_barrier(0);
#pragma unroll 1
    for (int t = 0; t < nt; t += 3) {
        PHASE(t, 0);
        PHASE(t + 1, 1);
        PHASE(t + 2, 2);
    }
#undef STAGE
#undef COMPUTE
#undef PHASE

    int gcolb = bn * 128 + wc * 64;             // wave col base
    int grb = bm * 128 + wr * 64;               // wave row base

    if constexpr (EPI == 0 || EPI == 2) {
        __syncthreads();   // safe to reuse staging LDS
        u16* ep = sm + wave * 4096;
        int h = (gcolb >> 6) & 7;
        bool isK = (EPI == 2) || (gcolb < 512);
#pragma unroll
        for (int m = 0; m < 4; m++)
#pragma unroll
            for (int n = 0; n < 4; n++) {
                float bv = bias[gcolb + n * 16 + fr];
#pragma unroll
                for (int r = 0; r < 4; r++) {
                    int wq = m * 16 + g * 4 + r;     // row within quadrant
                    int wcc = n * 16 + fr;           // col within quadrant
                    float val = acc[m][n][r] + bv;
                    if constexpr (EPI == 2)
                        val = 0.5f * val * (1.0f + erff(val * 0.70710678118f));
                    if (isK)
                        ep[wq * 64 + (wcc ^ ((wq & 7) << 3))] = f2bf(val);
                    else   // V: transpose in LDS -> [d][key]
                        ep[wcc * 64 + (wq ^ ((wcc & 7) << 3))] = f2bf(val);
                }
            }
#pragma unroll
        for (int rd = 0; rd < 8; rd++) {
            int row = rd * 8 + (lane >> 3);
            int ch = (lane & 7) ^ (row & 7);
            int4 v = *(const int4*)(ep + row * 64 + ch * 8);
            if constexpr (EPI == 2) {
                int grow = grb + row;
                *(int4*)(&((u16*)Cout)[(size_t)grow * Nn + gcolb + (lane & 7) * 8]) = v;
            } else {
                if (isK) {
                    int tok = grb + row;
                    int win = tok >> 9, key = tok & 511;
                    *(int4*)(&((u16*)Cout)[(((size_t)(win * 8 + h)) * 512 + key) * 64 + (lane & 7) * 8]) = v;
                } else {
                    int win = grb >> 9, key0 = grb & 511;   // 64 keys same window
                    *(int4*)(&((u16*)Cout2)[(((size_t)(win * 8 + h)) * 64 + row) * 512 + key0 + (lane & 7) * 8]) = v;
                }
            }
        }
    } else {
#pragma unroll
        for (int m = 0; m < 4; m++)
#pragma unroll
            for (int n = 0; n < 4; n++) {
                int col = gcolb + n * 16 + fr;
                float bv = bias[col];
#pragma unroll
                for (int r = 0; r < 4; r++) {
                    int row = grb + m * 16 + g * 4 + r;
                    float val = acc[m][n][r] + bv;
                    if constexpr (EPI == 1) {
                        int ri = win_to_img(row);
                        size_t o = (size_t)ri * 512 + col;
                        ((float*)Cout)[o] = val + resid[o];
                    } else {
                        size_t o = (size_t)row * 512 + col;
                        ((float*)Cout)[o] = val + resid[o];
                    }
                }
            }
    }
}

// Flash attention: 4096 blocks (XCD-chunk swizzled), 4 waves x 16 q-rows.
// kb:  bf16 [win][h][key 512][d 64]  (PLAIN)
// vtb: bf16 [win][h][d 64][key 512]  (PLAIN)
// Staging: global_load_lds w=16 with pre-swizzled SOURCE chunks (linear LDS
// dest); LDS content [row][c] = true[row][c^(row&7)], reads XOR-deswizzle.
__global__ __launch_bounds__(256, 3) void k_attn(const u16* __restrict__ qb,
                                                 const u16* __restrict__ kb,
                                                 const u16* __restrict__ vtb,
                                                 u16* __restrict__ o) {
    __shared__ u16 K0[4096], K1[4096], V0[4096], V1[4096];  // [row 64][64]
    __shared__ u16 Ps[64][72];
    int bid = blockIdx.x;
    int wg = (bid & 7) * 512 + (bid >> 3);   // bijective XCD chunking (4096%8==0)
    int qc = wg & 7;
    int pair = wg >> 3;
    int hh = pair & 7, win = pair >> 3;
    int wave = threadIdx.x >> 6, lane = threadIdx.x & 63;
    const u16* kbw = kb + ((size_t)(win * 8 + hh)) * 512 * 64;
    const u16* vtw = vtb + ((size_t)(win * 8 + hh)) * 64 * 512;

    const u16* qrow = qb + ((size_t)hh * 512 + qc * 64 + (wave << 4) + (lane & 15)) * 64 + (lane >> 4) * 8;
    bfrag aq0 = *(const bfrag*)(qrow);
    bfrag aq1 = *(const bfrag*)(qrow + 32);

    ffrag acc[4] = {};
    float m_run[4], l_run[4];
#pragma unroll
    for (int r = 0; r < 4; r++) { m_run[r] = -1e30f; l_run[r] = 0.0f; }

    int srow = lane >> 3;                        // sub-row within 8-row group
    int sxo = ((lane & 7) ^ srow) * 8;           // pre-swizzled source chunk
    int fr = lane & 15;
    int fkc = lane >> 4;                         // logical k-chunk 0..3
    int kx0 = (fkc ^ (fr & 7)) * 8;              // physical chunk, k 0..31
    int kx1 = ((fkc + 4) ^ (fr & 7)) * 8;        // k 32..63
    int arow = (wave << 4) + fr;

#define STAGE_KV(KS, VS, kc)                                                   \
    {                                                                          \
        GLOAD16(kbw + (size_t)((kc) * 64 + wave * 8 + srow) * 64 + sxo,        \
                KS + wave * 512);                                              \
        GLOAD16(kbw + (size_t)((kc) * 64 + 32 + wave * 8 + srow) * 64 + sxo,   \
                KS + 2048 + wave * 512);                                       \
        GLOAD16(vtw + (size_t)(wave * 8 + srow) * 512 + (kc) * 64 + sxo,       \
                VS + wave * 512);                                              \
        GLOAD16(vtw + (size_t)(32 + wave * 8 + srow) * 512 + (kc) * 64 + sxo,  \
                VS + 2048 + wave * 512);                                       \
    }
#define ATT_COMPUTE(KS, VS)                                                    \
    {                                                                          \
        ffrag s[4] = {};                                                       \
        _Pragma("unroll") for (int j = 0; j < 4; j++) {                        \
            bfrag b0 = *(const bfrag*)(KS + (j * 16 + fr) * 64 + kx0);         \
            s[j] = __builtin_amdgcn_mfma_f32_16x16x32_bf16(aq0, b0, s[j], 0, 0, 0); \
            bfrag b1 = *(const bfrag*)(KS + (j * 16 + fr) * 64 + kx1);         \
            s[j] = __builtin_amdgcn_mfma_f32_16x16x32_bf16(aq1, b1, s[j], 0, 0, 0); \
        }                                                                      \
        _Pragma("unroll") for (int r = 0; r < 4; r++) {                        \
            float mx = fmaxf(fmaxf(s[0][r], s[1][r]), fmaxf(s[2][r], s[3][r]));\
            _Pragma("unroll") for (int d = 1; d < 16; d <<= 1)                 \
                mx = fmaxf(mx, __shfl_xor(mx, d));                             \
            float mnew = fmaxf(m_run[r], mx);                                  \
            float alpha = __expf(m_run[r] - mnew);                             \
            m_run[r] = mnew;                                                   \
            float rs = 0.0f;                                                   \
            _Pragma("unroll") for (int j = 0; j < 4; j++) {                    \
                float p = __expf(s[j][r] - mnew);                              \
                s[j][r] = p;                                                   \
                rs += p;                                                       \
            }                                                                  \
            _Pragma("unroll") for (int d = 1; d < 16; d <<= 1)                 \
                rs += __shfl_xor(rs, d);                                       \
            l_run[r] = l_run[r] * alpha + rs;                                  \
            _Pragma("unroll") for (int j = 0; j < 4; j++) acc[j][r] *= alpha;  \
        }                                                                      \
        _Pragma("unroll") for (int j = 0; j < 4; j++)                          \
            _Pragma("unroll") for (int r = 0; r < 4; r++)                      \
                Ps[(wave << 4) + (lane >> 4) * 4 + r][j * 16 + fr] = f2bf(s[j][r]); \
        bfrag ap0 = *(const bfrag*)(&Ps[arow][fkc * 8]);                       \
        bfrag ap1 = *(const bfrag*)(&Ps[arow][32 + fkc * 8]);                  \
        _Pragma("unroll") for (int j = 0; j < 4; j++) {                        \
            bfrag v0 = *(const bfrag*)(VS + (j * 16 + fr) * 64 + kx0);         \
            acc[j] = __builtin_amdgcn_mfma_f32_16x16x32_bf16(ap0, v0, acc[j], 0, 0, 0); \
            bfrag v1 = *(const bfrag*)(VS + (j * 16 + fr) * 64 + kx1);         \
            acc[j] = __builtin_amdgcn_mfma_f32_16x16x32_bf16(ap1, v1, acc[j], 0, 0, 0); \
        }                                                                      \
    }

    STAGE_KV(K0, V0, 0);
    __syncthreads();
#pragma unroll 1
    for (int kc = 0; kc < 8; kc += 2) {
        if (kc + 1 < 8) STAGE_KV(K1, V1, kc + 1);
        ATT_COMPUTE(K0, V0);
        __syncthreads();
        if (kc + 2 < 8) STAGE_KV(K0, V0, kc + 2);
        ATT_COMPUTE(K1, V1);
        __syncthreads();
    }
#undef STAGE_KV
#undef ATT_COMPUTE

    int row0 = qc * 64 + (wave << 4) + (lane >> 4) * 4;
#pragma unroll
    for (int j = 0; j < 4; j++) {
        int col = hh * 64 + j * 16 + fr;
#pragma unroll
        for (int r = 0; r < 4; r++) {
            float val = acc[j][r] / l_run[r];
            o[((size_t)win * 512 + row0 + r) * 512 + col] = f2bf(val);
        }
    }
}

extern "C" void kernel_launch(void* const* d_in, const int* in_sizes, int n_in,
                              void* d_out, int out_size, void* d_ws, size_t ws_size,
                              hipStream_t stream) {
    const float* x      = (const float*)d_in[0];
    const float* q_ms   = (const float*)d_in[1];
    const float* n1w    = (const float*)d_in[2];
    const float* n1b    = (const float*)d_in[3];
    const float* kv_w   = (const float*)d_in[4];
    const float* kv_b   = (const float*)d_in[5];
    const float* proj_w = (const float*)d_in[6];
    const float* proj_b = (const float*)d_in[7];
    const float* n2w    = (const float*)d_in[8];
    const float* n2b    = (const float*)d_in[9];
    const float* fc1_w  = (const float*)d_in[10];
    const float* fc1_b  = (const float*)d_in[11];
    const float* fc2_w  = (const float*)d_in[12];
    const float* fc2_b  = (const float*)d_in[13];

    char* ws = (char*)d_ws;
    const size_t OFF_XNW = 0;           // bf16 [32768][512]   33,554,432 B
    const size_t OFF_KB  = 33554432;    // bf16 [64][8][512][64]  33,554,432 B
    const size_t OFF_VT  = 67108864;    // bf16 [64][8][64][512]  33,554,432 B
    const size_t OFF_O   = 100663296;   // bf16 [32768][512]   33,554,432 B
    const size_t OFF_HID = 0;           // bf16 [32768][2048] (aliases dead bufs)
    const size_t OFF_X1  = 134217728;   // f32  [32768][512]   67,108,864 B
    const size_t OFF_XN2 = 201326592;   // bf16 [32768][512]   33,554,432 B
    const size_t OFF_W   = 234881024;   // transposed weights + q
    u16* xnw = (u16*)(ws + OFF_XNW);
    u16* kbb = (u16*)(ws + OFF_KB);
    u16* vtb = (u16*)(ws + OFF_VT);
    u16* ob  = (u16*)(ws + OFF_O);
    u16* hid = (u16*)(ws + OFF_HID);
    float* x1 = (float*)(ws + OFF_X1);
    u16* xn2 = (u16*)(ws + OFF_XN2);
    u16* kv_wt   = (u16*)(ws + OFF_W);        // [1024][512]
    u16* proj_wt = kv_wt + 512 * 1024;        // [512][512]
    u16* fc1_wt  = proj_wt + 512 * 512;       // [2048][512]
    u16* fc2_wt  = fc1_wt + 512 * 2048;       // [512][2048]
    u16* qbf     = fc2_wt + 2048 * 512;       // [8][512][64]
    size_t need = OFF_W + (size_t)(512 * 1024 + 512 * 512 + 512 * 2048 + 2048 * 512 + 8 * 512 * 64) * 2;
    if (ws_size < need) return;

    k_ln<<<8192, 256, 0, stream>>>(x, n1w, n1b, xnw, 1);
    k_transpose<<<2048, 256, 0, stream>>>(kv_w, kv_wt, 512, 1024);
    k_transpose<<<1024, 256, 0, stream>>>(proj_w, proj_wt, 512, 512);
    k_transpose<<<4096, 256, 0, stream>>>(fc1_w, fc1_wt, 512, 2048);
    k_transpose<<<4096, 256, 0, stream>>>(fc2_w, fc2_wt, 2048, 512);
    k_qconv<<<1024, 256, 0, stream>>>(q_ms, qbf);

    k_gemm128<0><<<2048, 256, 0, stream>>>(xnw, kv_wt, kv_b, kbb, 512, 1024, nullptr, vtb);
    k_attn<<<dim3(4096), 256, 0, stream>>>(qbf, kbb, vtb, ob);
    k_gemm128<1><<<1024, 256, 0, stream>>>(ob, proj_wt, proj_b, x1, 512, 512, x, nullptr);
    k_ln<<<8192, 256, 0, stream>>>(x1, n2w, n2b, xn2, 0);
    k_gemm128<2><<<4096, 256, 0, stream>>>(xn2, fc1_wt, fc1_b, hid, 512, 2048, nullptr, nullptr);
    k_gemm128<3><<<1024, 256, 0, stream>>>(hid, fc2_wt, fc2_b, d_out, 2048, 512, x1, nullptr);
}